// Round 1
// baseline (262.770 us; speedup 1.0000x reference)
//
#include <hip/hip_runtime.h>
#include <cstdint>
#include <cstddef>

#define B_    8
#define N_    2048
#define FIN   128
#define FOUT  64
#define ALPHA 0.2f
#define NEG_BIG -9.0e15f

typedef __attribute__((ext_vector_type(8))) _Float16 half8;
typedef __attribute__((ext_vector_type(4))) float float4v;

// ---------------------------------------------------------------------------
// Kernel 1: wh = x @ W  (fp32 accumulate), store whT[b][f][j] as fp16,
//           s1 = wh@a1, s2 = wh@a2 (fp32).
// wave-per-row: lane = output feature, x row broadcast via scalar loads.
// ---------------------------------------------------------------------------
__global__ __launch_bounds__(256, 4) void k1_wh(
    const float* __restrict__ x, const float* __restrict__ W,
    const float* __restrict__ w2, _Float16* __restrict__ whT,
    float* __restrict__ s1, float* __restrict__ s2)
{
    int t = threadIdx.x, lane = t & 63, w = t >> 6;
    float a1 = w2[lane], a2 = w2[FOUT + lane];
    int rowBase = blockIdx.x * 32 + w * 8;   // 32 rows/block, 8 rows/wave
    for (int rr = 0; rr < 8; ++rr) {
        int row = __builtin_amdgcn_readfirstlane(rowBase + rr);  // wave-uniform
        const float* xr = x + (size_t)row * FIN;
        float acc = 0.f;
        #pragma unroll
        for (int k = 0; k < FIN; ++k)
            acc = fmaf(xr[k], W[k * FOUT + lane], acc);
        int b = row >> 11, j = row & (N_ - 1);
        whT[((size_t)b * FOUT + lane) * N_ + j] = (_Float16)acc;
        float p1 = acc * a1, p2 = acc * a2;
        #pragma unroll
        for (int m = 32; m >= 1; m >>= 1) {
            p1 += __shfl_xor(p1, m);
            p2 += __shfl_xor(p2, m);
        }
        if (lane == 0) { s1[row] = p1; s2[row] = p2; }
    }
}

// ---------------------------------------------------------------------------
// Kernel 2: flash-style masked softmax + PV via MFMA.
// Block = 16 rows, 4 waves split the j range (512 each). Same per-row upper
// bound m^ = leaky(s1_i + max_j s2_j) for every split -> partials merge by
// plain addition (softmax is shift-invariant; p<=1 guaranteed).
// A-frag: row = lane&15, k = (lane>>4)*8 + e. C/D: col = lane&15,
// row = (lane>>4)*4 + reg  [verified layouts, learn_hip m89/m120].
// ---------------------------------------------------------------------------
__global__ __launch_bounds__(256, 4) void k2_attn(
    const int* __restrict__ adj, const _Float16* __restrict__ whT,
    const float* __restrict__ s1, const float* __restrict__ s2,
    float* __restrict__ out)
{
    __shared__ float accL[4][16][68];   // [wave][row][feature], padded
    __shared__ float lL[4][16];
    __shared__ float smaxL[4];

    int t = threadIdx.x, lane = t & 63, w = t >> 6;
    int r0 = blockIdx.x * 16;           // 16 rows per block
    int b = r0 >> 11, i0 = r0 & (N_ - 1);

    // --- exact S2MAX over batch b (8 KB, L2-hot) ---
    const float4* s2v = (const float4*)(s2 + (size_t)b * N_);
    float4 ua = s2v[t], ub = s2v[t + 256];
    float vm = fmaxf(fmaxf(fmaxf(ua.x, ua.y), fmaxf(ua.z, ua.w)),
                     fmaxf(fmaxf(ub.x, ub.y), fmaxf(ub.z, ub.w)));
    #pragma unroll
    for (int m = 32; m >= 1; m >>= 1) vm = fmaxf(vm, __shfl_xor(vm, m));
    if (lane == 0) smaxL[w] = vm;
    __syncthreads();
    float s2max = fmaxf(fmaxf(smaxL[0], smaxL[1]), fmaxf(smaxL[2], smaxL[3]));

    int l15 = lane & 15, quad = lane >> 4;
    // A-row this lane owns:
    float s1i = s1[(size_t)b * N_ + i0 + l15];
    float mh  = s1i + s2max;
    mh = fmaxf(mh, ALPHA * mh);          // leaky(s1_i + s2max) >= true row max
    float negmh = -mh;

    float4v acc0 = {0,0,0,0}, acc1 = {0,0,0,0}, acc2 = {0,0,0,0}, acc3 = {0,0,0,0};
    float lsum = 0.f;

    const int jseg = w * 512;            // split-K across 4 waves
    const int*      adjp = adj + ((size_t)b * N_ + i0 + l15) * N_ + jseg + quad * 8;
    const float*    s2p  = s2  + (size_t)b * N_ + jseg + quad * 8;
    const _Float16* wp   = whT + (size_t)b * FOUT * N_ + (size_t)l15 * N_ + jseg + quad * 8;

    for (int c = 0; c < 16; ++c) {       // 16 chunks of 32 j
        int4   aj0 = *(const int4*)(adjp);
        int4   aj1 = *(const int4*)(adjp + 4);
        float4 sa  = *(const float4*)(s2p);
        float4 sb  = *(const float4*)(s2p + 4);
        adjp += 32; s2p += 32;

        int   aa[8] = {aj0.x, aj0.y, aj0.z, aj0.w, aj1.x, aj1.y, aj1.z, aj1.w};
        float ss[8] = {sa.x, sa.y, sa.z, sa.w, sb.x, sb.y, sb.z, sb.w};
        half8 af;
        #pragma unroll
        for (int e = 0; e < 8; ++e) {
            float v = s1i + ss[e];
            v = fmaxf(v, ALPHA * v);                 // leaky relu
            v = (aa[e] > 0) ? v : NEG_BIG;           // mask
            float tt = fmaxf(v + negmh, -76.f);      // floor: masked -> ~0
            float p = __expf(tt);                    // p in (0,1]
            lsum += p;
            af[e] = (_Float16)p;
        }
        half8 b0 = *(const half8*)(wp);
        half8 b1 = *(const half8*)(wp + 16 * N_);
        half8 b2 = *(const half8*)(wp + 32 * N_);
        half8 b3 = *(const half8*)(wp + 48 * N_);
        wp += 32;
        acc0 = __builtin_amdgcn_mfma_f32_16x16x32_f16(af, b0, acc0, 0, 0, 0);
        acc1 = __builtin_amdgcn_mfma_f32_16x16x32_f16(af, b1, acc1, 0, 0, 0);
        acc2 = __builtin_amdgcn_mfma_f32_16x16x32_f16(af, b2, acc2, 0, 0, 0);
        acc3 = __builtin_amdgcn_mfma_f32_16x16x32_f16(af, b3, acc3, 0, 0, 0);
    }

    // l: combine the 4 quads (they covered different k within this wave's seg)
    lsum += __shfl_xor(lsum, 16);
    lsum += __shfl_xor(lsum, 32);

    // C-frag -> LDS. col = lane&15 (feature-within-tile), row = quad*4+reg.
    #pragma unroll
    for (int reg = 0; reg < 4; ++reg) {
        int row = quad * 4 + reg;
        accL[w][row][ 0 + l15] = acc0[reg];
        accL[w][row][16 + l15] = acc1[reg];
        accL[w][row][32 + l15] = acc2[reg];
        accL[w][row][48 + l15] = acc3[reg];
    }
    if (quad == 0) lL[w][l15] = lsum;
    __syncthreads();

    // merge 4 K-splits (same m^ -> plain sums), normalize, ELU, store
    int f = t & 63, iq = t >> 6;
    #pragma unroll
    for (int rr = 0; rr < 4; ++rr) {
        int ii = iq * 4 + rr;
        float sum = accL[0][ii][f] + accL[1][ii][f] + accL[2][ii][f] + accL[3][ii][f];
        float lt  = lL[0][ii] + lL[1][ii] + lL[2][ii] + lL[3][ii];
        float val = sum / lt;
        val = (val > 0.f) ? val : (__expf(val) - 1.f);   // ELU
        out[((size_t)r0 + ii) * FOUT + f] = val;
    }
}

// ---------------------------------------------------------------------------
extern "C" void kernel_launch(void* const* d_in, const int* in_sizes, int n_in,
                              void* d_out, int out_size, void* d_ws, size_t ws_size,
                              hipStream_t stream) {
    const float* x   = (const float*)d_in[0];
    const int*   adj = (const int*)d_in[1];
    const float* W   = (const float*)d_in[2];
    const float* w2  = (const float*)d_in[3];
    float* out = (float*)d_out;

    _Float16* whT = (_Float16*)d_ws;                                  // 2 MiB
    float* s1 = (float*)((char*)d_ws + (size_t)B_ * FOUT * N_ * 2);   // 64 KiB
    float* s2 = s1 + (size_t)B_ * N_;                                 // 64 KiB

    k1_wh<<<(B_ * N_) / 32, 256, 0, stream>>>(x, W, w2, whT, s1, s2);
    k2_attn<<<(B_ * N_) / 16, 256, 0, stream>>>(adj, whT, s1, s2, out);
}

// Round 2
// 254.331 us; speedup vs baseline: 1.0332x; 1.0332x over previous
//
#include <hip/hip_runtime.h>
#include <cstdint>
#include <cstddef>

#define B_    8
#define N_    2048
#define FIN   128
#define FOUT  64
#define ALPHA 0.2f
#define NEG_BIG -9.0e15f

typedef __attribute__((ext_vector_type(8))) _Float16 half8;
typedef __attribute__((ext_vector_type(4))) float float4v;

// ---------------------------------------------------------------------------
// Kernel 1: wh = x @ W  (fp32 accumulate), store whT[b][f][j] as fp16,
//           s1 = wh@a1, s2 = wh@a2 (fp32).
// wave-per-row: lane = output feature, x row broadcast via scalar loads.
// ---------------------------------------------------------------------------
__global__ __launch_bounds__(256, 4) void k1_wh(
    const float* __restrict__ x, const float* __restrict__ W,
    const float* __restrict__ w2, _Float16* __restrict__ whT,
    float* __restrict__ s1, float* __restrict__ s2)
{
    int t = threadIdx.x, lane = t & 63, w = t >> 6;
    float a1 = w2[lane], a2 = w2[FOUT + lane];
    int rowBase = blockIdx.x * 32 + w * 8;   // 32 rows/block, 8 rows/wave
    for (int rr = 0; rr < 8; ++rr) {
        int row = __builtin_amdgcn_readfirstlane(rowBase + rr);  // wave-uniform
        const float* xr = x + (size_t)row * FIN;
        float acc = 0.f;
        #pragma unroll
        for (int k = 0; k < FIN; ++k)
            acc = fmaf(xr[k], W[k * FOUT + lane], acc);
        int b = row >> 11, j = row & (N_ - 1);
        whT[((size_t)b * FOUT + lane) * N_ + j] = (_Float16)acc;
        float p1 = acc * a1, p2 = acc * a2;
        #pragma unroll
        for (int m = 32; m >= 1; m >>= 1) {
            p1 += __shfl_xor(p1, m);
            p2 += __shfl_xor(p2, m);
        }
        if (lane == 0) { s1[row] = p1; s2[row] = p2; }
    }
}

// ---------------------------------------------------------------------------
// Kernel 2: flash-style masked softmax + PV via MFMA, LDS-staged p.
// Block = 16 rows x full j (2048), 4 waves.
//  p-phase : wave w owns rows w*4..w*4+3; adj read fully coalesced
//            (lane*32B contiguous, 2KB/instr); p (fp16) -> LDS pT[16][520].
//  MFMA    : wave w owns features w*16..w*16+15 over full K; A from LDS,
//            B from L2-resident whT; accumulator lives in registers.
// Same m^ = leaky(s1_i + max_j s2_j) upper bound -> no online rescaling.
// A-frag: row=lane&15, k=(lane>>4)*8+e. C/D: col=lane&15, row=(lane>>4)*4+reg.
// pT row stride 520 fp16 = 260 words: A-read lane (r,q) -> bank group
// 4*(r+q) mod 32, exactly 8 lanes per group = structural-min, conflict-free.
// ---------------------------------------------------------------------------
__global__ __launch_bounds__(256, 4) void k2_attn(
    const int* __restrict__ adj, const _Float16* __restrict__ whT,
    const float* __restrict__ s1, const float* __restrict__ s2,
    float* __restrict__ out)
{
    __shared__ __attribute__((aligned(16))) _Float16 pT[16][520];
    __shared__ float lL[16];
    __shared__ float smaxL[4];

    int t = threadIdx.x, lane = t & 63, w = t >> 6;
    int b = blockIdx.x >> 7;
    int i0 = (blockIdx.x & 127) << 4;

    // --- exact S2MAX over batch b (8 KB, L2-hot) ---
    const float4* s2v = (const float4*)(s2 + (size_t)b * N_);
    float4 ua = s2v[t], ub = s2v[t + 256];
    float vm = fmaxf(fmaxf(fmaxf(ua.x, ua.y), fmaxf(ua.z, ua.w)),
                     fmaxf(fmaxf(ub.x, ub.y), fmaxf(ub.z, ub.w)));
    #pragma unroll
    for (int m = 32; m >= 1; m >>= 1) vm = fmaxf(vm, __shfl_xor(vm, m));
    if (lane == 0) smaxL[w] = vm;
    __syncthreads();
    float s2max = fmaxf(fmaxf(smaxL[0], smaxL[1]), fmaxf(smaxL[2], smaxL[3]));

    int l15 = lane & 15, quad = lane >> 4;
    int f0 = w * 16;

    // p-phase per-row params (wave w owns rows w*4..w*4+3)
    float s1r[4], negmh[4], lacc[4];
    #pragma unroll
    for (int rr = 0; rr < 4; ++rr) {
        float sv = s1[(size_t)b * N_ + i0 + w * 4 + rr];  // wave-uniform
        float mh = sv + s2max;
        mh = fmaxf(mh, ALPHA * mh);      // leaky(s1_i + s2max) >= row max
        s1r[rr] = sv;
        negmh[rr] = -mh;
        lacc[rr] = 0.f;
    }

    float4v acc = {0, 0, 0, 0};
    const _Float16* wB = whT + ((size_t)b * FOUT + f0 + l15) * N_ + quad * 8;

    for (int jc = 0; jc < N_; jc += 512) {
        // s2 chunk: 8 consecutive floats per lane, reused across 4 rows
        const float* s2c = s2 + (size_t)b * N_ + jc + lane * 8;
        float4 sa = *(const float4*)s2c;
        float4 sb = *(const float4*)(s2c + 4);
        float ss[8] = {sa.x, sa.y, sa.z, sa.w, sb.x, sb.y, sb.z, sb.w};

        #pragma unroll
        for (int rr = 0; rr < 4; ++rr) {
            int r = w * 4 + rr;
            const int* ap = adj + ((size_t)b * N_ + i0 + r) * N_ + jc + lane * 8;
            int4 aj0 = *(const int4*)ap;
            int4 aj1 = *(const int4*)(ap + 4);
            int aa[8] = {aj0.x, aj0.y, aj0.z, aj0.w, aj1.x, aj1.y, aj1.z, aj1.w};
            half8 pf;
            float ls = 0.f;
            #pragma unroll
            for (int e = 0; e < 8; ++e) {
                float v = s1r[rr] + ss[e];
                v = fmaxf(v, ALPHA * v);                 // leaky relu
                v = (aa[e] > 0) ? v : NEG_BIG;           // mask
                float tt = fmaxf(v + negmh[rr], -76.f);  // masked -> exp ~ 0
                float p = __expf(tt);                    // p in (0,1]
                ls += p;
                pf[e] = (_Float16)p;
            }
            lacc[rr] += ls;
            *(half8*)&pT[r][lane * 8] = pf;              // contiguous b128
        }

        if (jc == N_ - 512) {
            // final row-sum reduction, before the barrier that publishes pT
            #pragma unroll
            for (int rr = 0; rr < 4; ++rr) {
                float v = lacc[rr];
                #pragma unroll
                for (int m = 32; m >= 1; m >>= 1) v += __shfl_xor(v, m);
                if (lane == 0) lL[w * 4 + rr] = v;
            }
        }
        __syncthreads();

        // MFMA phase: wave w's 16-feature group, K-chunk of 512
        const _Float16* wp = wB + jc;
        #pragma unroll
        for (int kk = 0; kk < 16; ++kk) {
            half8 af = *(const half8*)&pT[l15][kk * 32 + quad * 8];
            half8 bf = *(const half8*)(wp + kk * 32);
            acc = __builtin_amdgcn_mfma_f32_16x16x32_f16(af, bf, acc, 0, 0, 0);
        }
        __syncthreads();
    }

    // epilogue: normalize, ELU, store. D: row=quad*4+reg, col=f0+l15
    #pragma unroll
    for (int reg = 0; reg < 4; ++reg) {
        int row = quad * 4 + reg;
        float val = acc[reg] / lL[row];
        val = (val > 0.f) ? val : (__expf(val) - 1.f);   // ELU
        out[((size_t)b * N_ + i0 + row) * FOUT + f0 + l15] = val;
    }
}

// ---------------------------------------------------------------------------
extern "C" void kernel_launch(void* const* d_in, const int* in_sizes, int n_in,
                              void* d_out, int out_size, void* d_ws, size_t ws_size,
                              hipStream_t stream) {
    const float* x   = (const float*)d_in[0];
    const int*   adj = (const int*)d_in[1];
    const float* W   = (const float*)d_in[2];
    const float* w2  = (const float*)d_in[3];
    float* out = (float*)d_out;

    _Float16* whT = (_Float16*)d_ws;                                  // 2 MiB
    float* s1 = (float*)((char*)d_ws + (size_t)B_ * FOUT * N_ * 2);   // 64 KiB
    float* s2 = s1 + (size_t)B_ * N_;                                 // 64 KiB

    k1_wh<<<(B_ * N_) / 32, 256, 0, stream>>>(x, W, w2, whT, s1, s2);
    k2_attn<<<(B_ * N_) / 16, 256, 0, stream>>>(adj, whT, s1, s2, out);
}